// Round 8
// baseline (866.001 us; speedup 1.0000x reference)
//
#include <hip/hip_runtime.h>
#include <cstdint>
#include <cstddef>

// ---------------- problem constants ----------------
#define P_TOT    16384      // B*H*W = 4*64*64
#define CIN      1024
#define CMID     512
#define NA       9
#define NANC     147456     // P_TOT * NA
#define PRE_NMS  6000
#define POST_NMS 300
#define IOU_THR  0.7f
#define NWORDS   94         // ceil(6000/64)
#define NHCOPY   64         // histogram copies (contention spreading)

// output layout (floats): cls_pred | reg_pred | proposals
#define CLS_OFF  0
#define REG_OFF  147456
#define PROP_OFF 737280

// ---------------- workspace layout (bytes) ----------------
// Aliasing into the dead h region (h: 33.5 MB, dead after gemm2):
//   WS_MASK  @ 0       (4.5 MB, written by nmsmat, after rank)
//   WS_HISTN @ 8 MB    (16 MB, 64 histogram copies, written by decode)
// WS_WCOMB aliases WS_HIST (wcomb dead after gemm2; hist written later
// by hreduce). Lifetimes verified stream-ordered. Total ws ~39.5 MB.
#define WS_H        0u          // 16384*512*4   = 33554432
#define WS_MASK     0u          // 6000*94*8     = 4512000   (aliases h)
#define WS_HISTN    8388608u    // 64*65536*4    = 16777216  (aliases h)
#define WS_LOGITS   33554432u   // 16384*48*4    = 3145728
#define WS_BOXES    36700160u   // 147456*4*4    = 2359296
#define WS_HIST     39059456u   // 65536*4       = 262144
#define WS_WCOMB    39059456u   // 512*48*4      = 98304     (aliases hist)
#define WS_META     39321600u   // 64*4          = 256   (meta[0]=cnt, meta[1]=T)
#define WS_COLL     39321856u   // 8192*8        = 65536
#define WS_SBOX     39387392u   // 6000*16       = 96000  -> end ~39.5 MB
#define CAP_COLL    8192

__device__ __forceinline__ int imin(int a, int b) { return a < b ? a : b; }

// async global->LDS, 16B per lane. LDS dest must be wave-uniform base +
// lane*16 -> per-lane pointer linear in thread id.
__device__ __forceinline__ void gld_lds16(const float* g, float* l) {
    __builtin_amdgcn_global_load_lds(
        (const __attribute__((address_space(1))) void*)g,
        (__attribute__((address_space(3))) void*)l,
        16, 0, 0);
}

// =====================================================================
// GEMM1: h[16384x512] = relu(feats[16384x1024] @ w_bneck[1024x512] + b)
// fp32 vector GEMM (fp32 REQUIRED: NMS ordering sensitive to ~1e-6 score
// gaps; bf16/MFMA noise would reorder proposals -> absmax ~0.5).
// 128x128 tile, 8x8 microtile, unroll 2, B via global_load_lds, dbuf.
// R7 post-mortem: with no occupancy attr the backend targeted 8 waves/EU
// (64-VGPR cap) and parked the 64 accumulators in AGPRs -> a
// v_accvgpr_read/write pair per FMA ate the entire density win (time
// bit-identical to R6). amdgpu_waves_per_eu(1,2): grid only supplies
// 2 blocks/CU (=2 waves/EU), so a ~130-VGPR allocation costs nothing.
// Spill sentinel: WRITE_SIZE must stay 32768 KB.
// =====================================================================
__global__ __launch_bounds__(256)
__attribute__((amdgpu_waves_per_eu(1, 2)))
void gemm1_kernel(
    const float* __restrict__ A, const float* __restrict__ Bw,
    const float* __restrict__ bias, float* __restrict__ C)
{
    __shared__ float As[2][16][132];   // [buf][k][m] transposed, padded
    __shared__ float Bs[2][16][128];   // [buf][k][n]  (no pad: load_lds linear)

    const int t  = threadIdx.x;
    const int m0 = blockIdx.x * 128;
    const int n0 = blockIdx.y * 128;
    const int tx = t & 15;             // n-dir: cols tx*4, 64+tx*4
    const int ty = t >> 4;             // m-dir: rows ty*4..+3, 64+ty*4..+3

    const int ar0 = t >> 2;            // A row in tile (0..63), second +64
    const int ac0 = (t & 3) * 4;       // A col in tile (k)

    const float* asrc0 = A + (size_t)(m0 + ar0) * CIN + ac0;
    const float* asrc1 = asrc0 + (size_t)64 * CIN;
    const float* bsrc  = Bw + (size_t)(t >> 5) * CMID + n0 + (t & 31) * 4;
    float* bdst0 = &Bs[0][0][0] + t * 4;   // byte off = 16*t (lane-linear)
    float* bdst1 = &Bs[1][0][0] + t * 4;

    float4 c0a{0,0,0,0}, c0b{0,0,0,0}, c1a{0,0,0,0}, c1b{0,0,0,0};
    float4 c2a{0,0,0,0}, c2b{0,0,0,0}, c3a{0,0,0,0}, c3b{0,0,0,0};
    float4 c4a{0,0,0,0}, c4b{0,0,0,0}, c5a{0,0,0,0}, c5b{0,0,0,0};
    float4 c6a{0,0,0,0}, c6b{0,0,0,0}, c7a{0,0,0,0}, c7b{0,0,0,0};

    // ---- prologue: tile 0 into buf 0 ----
    gld_lds16(bsrc, bdst0);
    gld_lds16(bsrc + 8 * CMID, bdst0 + 1024);
    float4 pa0 = *(const float4*)(asrc0);
    float4 pa1 = *(const float4*)(asrc1);
    As[0][ac0 + 0][ar0] = pa0.x; As[0][ac0 + 1][ar0] = pa0.y;
    As[0][ac0 + 2][ar0] = pa0.z; As[0][ac0 + 3][ar0] = pa0.w;
    As[0][ac0 + 0][ar0 + 64] = pa1.x; As[0][ac0 + 1][ar0 + 64] = pa1.y;
    As[0][ac0 + 2][ar0 + 64] = pa1.z; As[0][ac0 + 3][ar0 + 64] = pa1.w;
    __syncthreads();

#define FMA4(acc, s, b) { acc.x += (s)*(b).x; acc.y += (s)*(b).y; \
                          acc.z += (s)*(b).z; acc.w += (s)*(b).w; }

    for (int kt = 0; kt < 64; ++kt) {
        const int cur = kt & 1, nxt = cur ^ 1;
        if (kt < 63) {
            const int k0 = (kt + 1) * 16;
            float* bd = nxt ? bdst1 : bdst0;
            gld_lds16(bsrc + (size_t)k0 * CMID, bd);
            gld_lds16(bsrc + (size_t)(k0 + 8) * CMID, bd + 1024);
            pa0 = *(const float4*)(asrc0 + k0);
            pa1 = *(const float4*)(asrc1 + k0);
        }
#pragma unroll 2
        for (int kk = 0; kk < 16; ++kk) {
            float4 a0 = *(const float4*)&As[cur][kk][ty * 4];
            float4 a1 = *(const float4*)&As[cur][kk][64 + ty * 4];
            float4 b0 = *(const float4*)&Bs[cur][kk][tx * 4];
            float4 b1 = *(const float4*)&Bs[cur][kk][64 + tx * 4];
            FMA4(c0a, a0.x, b0) FMA4(c0b, a0.x, b1)
            FMA4(c1a, a0.y, b0) FMA4(c1b, a0.y, b1)
            FMA4(c2a, a0.z, b0) FMA4(c2b, a0.z, b1)
            FMA4(c3a, a0.w, b0) FMA4(c3b, a0.w, b1)
            FMA4(c4a, a1.x, b0) FMA4(c4b, a1.x, b1)
            FMA4(c5a, a1.y, b0) FMA4(c5b, a1.y, b1)
            FMA4(c6a, a1.z, b0) FMA4(c6b, a1.z, b1)
            FMA4(c7a, a1.w, b0) FMA4(c7b, a1.w, b1)
        }
        if (kt < 63) {
            As[nxt][ac0 + 0][ar0] = pa0.x; As[nxt][ac0 + 1][ar0] = pa0.y;
            As[nxt][ac0 + 2][ar0] = pa0.z; As[nxt][ac0 + 3][ar0] = pa0.w;
            As[nxt][ac0 + 0][ar0 + 64] = pa1.x; As[nxt][ac0 + 1][ar0 + 64] = pa1.y;
            As[nxt][ac0 + 2][ar0 + 64] = pa1.z; As[nxt][ac0 + 3][ar0 + 64] = pa1.w;
        }
        __syncthreads();
    }
#undef FMA4

    const float4 bias0 = *(const float4*)(bias + n0 + tx * 4);
    const float4 bias1 = *(const float4*)(bias + n0 + 64 + tx * 4);
#define STROW(row, ca, cb) { \
    float4 o; \
    o.x = fmaxf(ca.x + bias0.x, 0.f); o.y = fmaxf(ca.y + bias0.y, 0.f); \
    o.z = fmaxf(ca.z + bias0.z, 0.f); o.w = fmaxf(ca.w + bias0.w, 0.f); \
    *(float4*)(C + (size_t)(row) * CMID + n0 + tx * 4) = o; \
    o.x = fmaxf(cb.x + bias1.x, 0.f); o.y = fmaxf(cb.y + bias1.y, 0.f); \
    o.z = fmaxf(cb.z + bias1.z, 0.f); o.w = fmaxf(cb.w + bias1.w, 0.f); \
    *(float4*)(C + (size_t)(row) * CMID + n0 + 64 + tx * 4) = o; }

    const int mr = m0 + ty * 4;
    STROW(mr + 0, c0a, c0b)   STROW(mr + 1, c1a, c1b)
    STROW(mr + 2, c2a, c2b)   STROW(mr + 3, c3a, c3b)
    STROW(mr + 64, c4a, c4b)  STROW(mr + 65, c5a, c5b)
    STROW(mr + 66, c6a, c6b)  STROW(mr + 67, c7a, c7b)
#undef STROW
}

// =====================================================================
// wprep: combined weight matrix wcomb[512][48]: cols 0..8 = w_cls,
// 9..44 = w_reg, 45..47 = 0.
// =====================================================================
__global__ __launch_bounds__(256) void wprep_kernel(
    const float* __restrict__ wcls, const float* __restrict__ wreg,
    float* __restrict__ wcomb)
{
    int i = blockIdx.x * 256 + threadIdx.x;    // < 24576
    int k = i / 48, o = i - k * 48;
    float v = 0.f;
    if (o < 9)       v = wcls[k * 9 + o];
    else if (o < 45) v = wreg[k * 36 + (o - 9)];
    wcomb[i] = v;
}

// =====================================================================
// GEMM2: logits[16384 x 48(45)] = h @ wcomb. 64 px/block, 256 blocks,
// 12 outs/thread.
// =====================================================================
__global__ __launch_bounds__(256) void gemm2_kernel(
    const float* __restrict__ h, const float* __restrict__ wcomb,
    const float* __restrict__ bcls, const float* __restrict__ breg,
    float* __restrict__ logits)
{
    __shared__ float hS[64][33];   // padded
    __shared__ float wS[32][48];

    const int t  = threadIdx.x;
    const int p0 = blockIdx.x * 64;
    const int px = t & 63;
    const int og = t >> 6;          // 0..3 -> outs og*12 .. og*12+11

    const int hr = t >> 2;          // stage row 0..63
    const int hc = (t & 3) * 4;     // stage col

    float acc[12] = {};

    for (int kt = 0; kt < 16; ++kt) {
        const int k0 = kt * 32;
        {   // stage h tile 64x32 (2 float4/thread)
            const float* hp = h + (size_t)(p0 + hr) * CMID + k0 + hc;
            float4 v0 = *(const float4*)(hp);
            float4 v1 = *(const float4*)(hp + 16);
            hS[hr][hc + 0] = v0.x; hS[hr][hc + 1] = v0.y;
            hS[hr][hc + 2] = v0.z; hS[hr][hc + 3] = v0.w;
            hS[hr][16 + hc + 0] = v1.x; hS[hr][16 + hc + 1] = v1.y;
            hS[hr][16 + hc + 2] = v1.z; hS[hr][16 + hc + 3] = v1.w;
        }
        {   // stage w tile 32x48 = 384 float4
            int idx = t;
            if (idx < 384) {
                int kk = idx / 12, o4 = (idx - kk * 12) * 4;
                *(float4*)&wS[kk][o4] = *(const float4*)&wcomb[(size_t)(k0 + kk) * 48 + o4];
            }
            idx = t + 256;
            if (idx < 384) {
                int kk = idx / 12, o4 = (idx - kk * 12) * 4;
                *(float4*)&wS[kk][o4] = *(const float4*)&wcomb[(size_t)(k0 + kk) * 48 + o4];
            }
        }
        __syncthreads();
#pragma unroll 4
        for (int kk = 0; kk < 32; ++kk) {
            float hv = hS[px][kk];
            float4 w0 = *(const float4*)&wS[kk][og * 12];
            float4 w1 = *(const float4*)&wS[kk][og * 12 + 4];
            float4 w2 = *(const float4*)&wS[kk][og * 12 + 8];
            acc[0] += hv * w0.x; acc[1]  += hv * w0.y; acc[2]  += hv * w0.z; acc[3]  += hv * w0.w;
            acc[4] += hv * w1.x; acc[5]  += hv * w1.y; acc[6]  += hv * w1.z; acc[7]  += hv * w1.w;
            acc[8] += hv * w2.x; acc[9]  += hv * w2.y; acc[10] += hv * w2.z; acc[11] += hv * w2.w;
        }
        __syncthreads();
    }
#pragma unroll
    for (int c = 0; c < 12; ++c) {
        int o = og * 12 + c;
        if (o < 45) {
            float bv = (o < 9) ? bcls[o] : breg[o - 9];
            logits[(size_t)(p0 + px) * 48 + o] = acc[c] + bv;
        }
    }
}

// =====================================================================
// Decode: sigmoid -> cls_pred out; raw reg -> reg_pred out; box decode
// (clip [0,1]) -> boxes ws; 64-copy histogram of score upper-16 bits.
// =====================================================================
__global__ __launch_bounds__(256) void decode_kernel(
    const float* __restrict__ logits, const float4* __restrict__ ancs,
    float* __restrict__ out, float4* __restrict__ boxes,
    unsigned int* __restrict__ histN)
{
    int i = blockIdx.x * 256 + threadIdx.x;     // < 147456
    int p = i / 9, a = i - p * 9;
    const float* lrow = logits + (size_t)p * 48;
    float lg = lrow[a];
    float score = 1.f / (1.f + expf(-lg));
    out[CLS_OFF + i] = score;

    float r0 = lrow[9 + a * 4 + 0];
    float r1 = lrow[9 + a * 4 + 1];
    float r2 = lrow[9 + a * 4 + 2];
    float r3 = lrow[9 + a * 4 + 3];
    float4 rg; rg.x = r0; rg.y = r1; rg.z = r2; rg.w = r3;
    *(float4*)(out + REG_OFF + (size_t)i * 4) = rg;

    float4 an = ancs[i];
    float cx = an.x + r0 * an.z;
    float cy = an.y + r1 * an.w;
    float ww = an.z * expf(r2);
    float hh = an.w * expf(r3);
    float4 bb;
    bb.x = fminf(fmaxf(cx - ww * 0.5f, 0.f), 1.f);
    bb.y = fminf(fmaxf(cy - hh * 0.5f, 0.f), 1.f);
    bb.z = fminf(fmaxf(cx + ww * 0.5f, 0.f), 1.f);
    bb.w = fminf(fmaxf(cy + hh * 0.5f, 0.f), 1.f);
    boxes[i] = bb;

    unsigned int sb = __float_as_uint(score);   // positive -> bit-monotone
    atomicAdd(&histN[(unsigned)(blockIdx.x & (NHCOPY - 1)) * 65536u + (sb >> 16)], 1u);
}

// =====================================================================
// Histogram reduce: hist[b] = sum over 64 copies.
// =====================================================================
__global__ __launch_bounds__(256) void hreduce_kernel(
    const unsigned int* __restrict__ histN, unsigned int* __restrict__ hist)
{
    int b = blockIdx.x * 256 + threadIdx.x;    // < 65536
    unsigned int s = 0;
#pragma unroll 8
    for (int c = 0; c < NHCOPY; ++c) s += histN[(unsigned)c * 65536u + b];
    hist[b] = s;
}

// =====================================================================
// Scan: find threshold bin T = max bin with cum(>=T) >= PRE_NMS.
// =====================================================================
__global__ __launch_bounds__(256) void scan_kernel(
    const unsigned int* __restrict__ hist, unsigned int* __restrict__ meta)
{
    __shared__ unsigned int sums[256];
    __shared__ unsigned int sc[256];
    __shared__ unsigned int sc2[256];
    __shared__ int cstar;
    __shared__ unsigned int saShared;
    __shared__ int tbin;

    int t = threadIdx.x;
    if (t == 0) tbin = -1;

    unsigned int s = 0;
    int base = t << 8;
    for (int b = 0; b < 256; b += 4) {
        uint4 v = *(const uint4*)(hist + base + b);
        s += v.x + v.y + v.z + v.w;
    }
    sums[t] = s;
    __syncthreads();

    sc[t] = sums[255 - t];
    __syncthreads();
    for (int off = 1; off < 256; off <<= 1) {
        unsigned int v = sc[t];
        unsigned int add = (t >= off) ? sc[t - off] : 0u;
        __syncthreads();
        sc[t] = v + add;
        __syncthreads();
    }
    {
        unsigned int sa = (t == 255) ? 0u : sc[254 - t];
        if (sa < PRE_NMS && sa + sums[t] >= PRE_NMS) { cstar = t; saShared = sa; }
    }
    __syncthreads();

    int c = cstar;
    unsigned int SA = saShared;
    sc2[t] = hist[c * 256 + 255 - t];
    __syncthreads();
    for (int off = 1; off < 256; off <<= 1) {
        unsigned int v = sc2[t];
        unsigned int add = (t >= off) ? sc2[t - off] : 0u;
        __syncthreads();
        sc2[t] = v + add;
        __syncthreads();
    }
    {
        unsigned int si = sc2[255 - t];
        int cand = (SA + si >= PRE_NMS) ? t : -1;
        atomicMax(&tbin, cand);
    }
    __syncthreads();
    if (t == 0) meta[1] = (unsigned int)(c * 256 + tbin);
}

// =====================================================================
// Collect: all anchors with score bin >= T -> composite sort keys.
// key = score_bits<<32 | (0xFFFFFFFF - idx): larger == (higher score,
// then lower idx) -> matches stable argsort(-score).
// =====================================================================
__global__ __launch_bounds__(256) void collect_kernel(
    const float* __restrict__ scores, const unsigned int* __restrict__ meta,
    unsigned long long* __restrict__ coll, unsigned int* __restrict__ cnt)
{
    int i = blockIdx.x * 256 + threadIdx.x;
    unsigned int T = meta[1];
    unsigned int sb = __float_as_uint(scores[i]);
    if ((sb >> 16) >= T) {
        unsigned int pos = atomicAdd(cnt, 1u);
        if (pos < CAP_COLL)
            coll[pos] = ((unsigned long long)sb << 32) |
                        (unsigned long long)(0xFFFFFFFFu - (unsigned int)i);
    }
}

// =====================================================================
// Rank: rank(k) = #{keys > k} (keys unique via idx tiebreak) -> exact
// permutation; scatter box to sorted slot.
// R7 post-mortem: LDS-staged version did 8192 scalar ds_read per thread
// = 16.7 MB LDS traffic per block ~ 80us. The scan index is WAVE-UNIFORM
// -> read via the SCALAR path (s_load through constant cache): ~2 VALU
// ops per key, ~15us, zero LDS.
// =====================================================================
__global__ __launch_bounds__(256) void rank_kernel(
    const unsigned long long* __restrict__ coll,
    const unsigned int* __restrict__ cnt,
    const float4* __restrict__ boxes, float4* __restrict__ sboxes)
{
    const int t = threadIdx.x;
    const int gid = blockIdx.x * 256 + t;
    unsigned int n = cnt[0];
    if (n > CAP_COLL) n = CAP_COLL;
    unsigned long long me = (gid < (int)n) ? coll[gid] : 0ULL;
    int rank = 0;
    unsigned int j = 0;
    for (; j + 8 <= n; j += 8) {     // uniform indices -> s_load_dwordx16
        unsigned long long k0 = coll[j + 0], k1 = coll[j + 1];
        unsigned long long k2 = coll[j + 2], k3 = coll[j + 3];
        unsigned long long k4 = coll[j + 4], k5 = coll[j + 5];
        unsigned long long k6 = coll[j + 6], k7 = coll[j + 7];
        rank += (int)(k0 > me) + (int)(k1 > me) + (int)(k2 > me) + (int)(k3 > me)
              + (int)(k4 > me) + (int)(k5 > me) + (int)(k6 > me) + (int)(k7 > me);
    }
    for (; j < n; ++j) rank += (int)(coll[j] > me);

    if (gid < (int)n && rank < PRE_NMS) {
        unsigned int idx = 0xFFFFFFFFu - (unsigned int)(me & 0xFFFFFFFFULL);
        if (idx > NANC - 1) idx = NANC - 1;   // safety clamp
        sboxes[rank] = boxes[idx];
    }
}

// =====================================================================
// NMS matrix build: strict-upper suppression bitmask.
// mask[r][cb] bit i set <=> j = cb*64+i, j > r, IoU(r,j) > 0.7.
// =====================================================================
__global__ __launch_bounds__(64) void nmsmat_kernel(
    const float4* __restrict__ sboxes, unsigned long long* __restrict__ mask)
{
    const int rb = blockIdx.x, cb = blockIdx.y;
    if (cb < rb) return;
    __shared__ float cx1[64], cy1[64], cx2[64], cy2[64], car[64];

    const int t = threadIdx.x;
    const int c = cb * 64 + t;
    float4 b = (c < PRE_NMS) ? sboxes[c] : make_float4(0.f, 0.f, 0.f, 0.f);
    cx1[t] = b.x; cy1[t] = b.y; cx2[t] = b.z; cy2[t] = b.w;
    car[t] = (b.z - b.x) * (b.w - b.y);
    __syncthreads();

    const int r = rb * 64 + t;
    if (r >= PRE_NMS) return;
    const float4 rbx = sboxes[r];
    const float ra = (rbx.z - rbx.x) * (rbx.w - rbx.y);

    unsigned long long w = 0ULL;
#pragma unroll 8
    for (int i = 0; i < 64; ++i) {
        int j = cb * 64 + i;
        float iw = fmaxf(fminf(rbx.z, cx2[i]) - fmaxf(rbx.x, cx1[i]), 0.f);
        float ih = fmaxf(fminf(rbx.w, cy2[i]) - fmaxf(rbx.y, cy1[i]), 0.f);
        float inter = iw * ih;
        float uni = ra + car[i] - inter;
        float iou = (uni > 0.f) ? (inter / uni) : 0.f;   // dummy j>=6000 -> 0
        if (iou > IOU_THR && j > r) w |= (1ULL << i);
    }
    mask[(size_t)r * NWORDS + cb] = w;
}

// =====================================================================
// NMS resolve: ONE wave, valid bitmask in registers (lane t owns words
// 2t, 2t+1). Row fetched as ONE dwordx4 per lane (row base 752B, 16B
// aligned); words < wg (incl. never-written lower-triangle poison) are
// discarded by the predicate AFTER the load. __ballot arg must be a
// bool-ized compare (R4 truncation bug).
// =====================================================================
__global__ __launch_bounds__(64) void nmsresolve_kernel(
    const float4* __restrict__ sboxes,
    const unsigned long long* __restrict__ mask,
    float* __restrict__ prop)
{
    const int t = threadIdx.x;      // one wave
    for (int j = t; j < POST_NMS * 4; j += 64) prop[j] = 0.f;

    const int w0 = 2 * t, w1 = 2 * t + 1;
    unsigned long long v0 = 0ULL, v1 = 0ULL;
    if (w0 < 93) v0 = ~0ULL; else if (w0 == 93) v0 = (1ULL << 48) - 1ULL;
    if (w1 < 93) v1 = ~0ULL; else if (w1 == 93) v1 = (1ULL << 48) - 1ULL;

    int cnt = 0;
    while (cnt < POST_NMS) {
        int c = 0x7fffffff;
        if (v0) c = (w0 << 6) + __builtin_ctzll(v0);
        else if (v1) c = (w1 << 6) + __builtin_ctzll(v1);
        unsigned long long bal = __ballot((v0 | v1) != 0ULL);
        if (!bal) break;
        int F = __builtin_ctzll(bal);
        int g = __shfl(c, F, 64);
        const int wg = g >> 6, bg = g & 63;

        if (t == 0) {
            float4 bb = sboxes[g];
            *(float4*)(prop + cnt * 4) = bb;
        }
        unsigned long long mx = 0ULL, my = 0ULL;
        if (t < 47) {   // 94 words = 47 ulonglong2
            const ulonglong2* row2 = (const ulonglong2*)(mask + (size_t)g * NWORDS);
            ulonglong2 mm = row2[t];
            mx = mm.x; my = mm.y;
        }
        unsigned long long m0 = (w0 >= wg) ? mx : 0ULL;
        unsigned long long m1 = (w1 >= wg) ? my : 0ULL;
        v0 &= ~m0; v1 &= ~m1;
        if (w0 == wg) v0 &= ~(1ULL << bg);
        if (w1 == wg) v1 &= ~(1ULL << bg);
        ++cnt;
    }
}

// =====================================================================
extern "C" void kernel_launch(void* const* d_in, const int* in_sizes, int n_in,
                              void* d_out, int out_size, void* d_ws, size_t ws_size,
                              hipStream_t stream)
{
    const float*  feats   = (const float*)d_in[0];
    const float4* ancs    = (const float4*)d_in[1];
    // d_in[2] = ancs_valid (unused by reference)
    const float*  w_bneck = (const float*)d_in[3];
    const float*  b_bneck = (const float*)d_in[4];
    const float*  w_cls   = (const float*)d_in[5];
    const float*  b_cls   = (const float*)d_in[6];
    const float*  w_reg   = (const float*)d_in[7];
    const float*  b_reg   = (const float*)d_in[8];

    float* out = (float*)d_out;
    char*  ws  = (char*)d_ws;
    float*              h      = (float*)(ws + WS_H);
    float*              logits = (float*)(ws + WS_LOGITS);
    float4*             boxes  = (float4*)(ws + WS_BOXES);
    unsigned int*       histN  = (unsigned int*)(ws + WS_HISTN); // aliases h
    unsigned int*       hist   = (unsigned int*)(ws + WS_HIST);
    float*              wcomb  = (float*)(ws + WS_WCOMB);        // aliases hist
    unsigned int*       meta   = (unsigned int*)(ws + WS_META);
    unsigned long long* coll   = (unsigned long long*)(ws + WS_COLL);
    float4*             sboxes = (float4*)(ws + WS_SBOX);
    unsigned long long* mask   = (unsigned long long*)(ws + WS_MASK); // aliases h

    hipMemsetAsync(ws + WS_META, 0, 256, stream);

    wprep_kernel<<<96, 256, 0, stream>>>(w_cls, w_reg, wcomb);
    gemm1_kernel<<<dim3(128, 4), 256, 0, stream>>>(feats, w_bneck, b_bneck, h);
    gemm2_kernel<<<256, 256, 0, stream>>>(h, wcomb, b_cls, b_reg, logits);
    // histN region (aliases h) becomes dead only after gemm2 completes
    hipMemsetAsync(ws + WS_HISTN, 0, (size_t)NHCOPY * 65536 * 4, stream);
    decode_kernel<<<576, 256, 0, stream>>>(logits, ancs, out, boxes, histN);
    hreduce_kernel<<<256, 256, 0, stream>>>(histN, hist);
    scan_kernel<<<1, 256, 0, stream>>>(hist, meta);
    collect_kernel<<<576, 256, 0, stream>>>(out, meta, coll, &meta[0]);
    rank_kernel<<<32, 256, 0, stream>>>(coll, meta, boxes, sboxes);
    nmsmat_kernel<<<dim3(94, 94), 64, 0, stream>>>(sboxes, mask);
    nmsresolve_kernel<<<1, 64, 0, stream>>>(sboxes, mask, out + PROP_OFF);
}

// Round 9
// 648.692 us; speedup vs baseline: 1.3350x; 1.3350x over previous
//
#include <hip/hip_runtime.h>
#include <cstdint>
#include <cstddef>

// ---------------- problem constants ----------------
#define P_TOT    16384      // B*H*W = 4*64*64
#define CIN      1024
#define CMID     512
#define NA       9
#define NANC     147456     // P_TOT * NA
#define PRE_NMS  6000
#define POST_NMS 300
#define IOU_THR  0.7f
#define NWORDS   94         // ceil(6000/64)
#define NHCOPY   64         // histogram copies (contention spreading)

// output layout (floats): cls_pred | reg_pred | proposals
#define CLS_OFF  0
#define REG_OFF  147456
#define PROP_OFF 737280

// ---------------- workspace layout (bytes) ----------------
// Aliasing into the dead h region (h: 33.5 MB, dead after gemm2):
//   WS_MASK  @ 0       (4.5 MB, written by nmsmat, after rank)
//   WS_HISTN @ 8 MB    (16 MB, 64 histogram copies, written by decode)
// WS_WCOMB aliases WS_HIST (wcomb dead after gemm2; hist written later
// by hreduce). Lifetimes verified stream-ordered. Total ws ~39.5 MB.
#define WS_H        0u          // 16384*512*4   = 33554432
#define WS_MASK     0u          // 6000*94*8     = 4512000   (aliases h)
#define WS_HISTN    8388608u    // 64*65536*4    = 16777216  (aliases h)
#define WS_LOGITS   33554432u   // 16384*48*4    = 3145728
#define WS_BOXES    36700160u   // 147456*4*4    = 2359296
#define WS_HIST     39059456u   // 65536*4       = 262144
#define WS_WCOMB    39059456u   // 512*48*4      = 98304     (aliases hist)
#define WS_META     39321600u   // 64*4          = 256   (meta[0]=cnt, meta[1]=T)
#define WS_COLL     39321856u   // 8192*8        = 65536
#define WS_SBOX     39387392u   // 6000*16       = 96000  -> end ~39.5 MB
#define CAP_COLL    8192

__device__ __forceinline__ int imin(int a, int b) { return a < b ? a : b; }

// async global->LDS, 16B per lane. LDS dest must be wave-uniform base +
// lane*16 -> per-lane pointer linear in thread id.
__device__ __forceinline__ void gld_lds16(const float* g, float* l) {
    __builtin_amdgcn_global_load_lds(
        (const __attribute__((address_space(1))) void*)g,
        (__attribute__((address_space(3))) void*)l,
        16, 0, 0);
}

// =====================================================================
// GEMM1: h[16384x512] = relu(feats[16384x1024] @ w_bneck[1024x512] + b)
// fp32 vector GEMM (fp32 REQUIRED: NMS ordering sensitive to ~1e-6 score
// gaps; bf16/MFMA noise would reorder proposals -> absmax ~0.5).
// 128x128 tile, 8x8 microtile, unroll 2, B via global_load_lds, dbuf.
// amdgpu_waves_per_eu(1,2): without it the backend targeted 8 waves/EU
// (64-VGPR cap) and parked the 64 accumulators in AGPRs (R7, time
// identical to R6). Grid supplies only 2 blocks/CU anyway.
// Spill sentinel: WRITE_SIZE must stay 32768 KB.
// =====================================================================
__global__ __launch_bounds__(256)
__attribute__((amdgpu_waves_per_eu(1, 2)))
void gemm1_kernel(
    const float* __restrict__ A, const float* __restrict__ Bw,
    const float* __restrict__ bias, float* __restrict__ C)
{
    __shared__ float As[2][16][132];   // [buf][k][m] transposed, padded
    __shared__ float Bs[2][16][128];   // [buf][k][n]  (no pad: load_lds linear)

    const int t  = threadIdx.x;
    const int m0 = blockIdx.x * 128;
    const int n0 = blockIdx.y * 128;
    const int tx = t & 15;             // n-dir: cols tx*4, 64+tx*4
    const int ty = t >> 4;             // m-dir: rows ty*4..+3, 64+ty*4..+3

    const int ar0 = t >> 2;            // A row in tile (0..63), second +64
    const int ac0 = (t & 3) * 4;       // A col in tile (k)

    const float* asrc0 = A + (size_t)(m0 + ar0) * CIN + ac0;
    const float* asrc1 = asrc0 + (size_t)64 * CIN;
    const float* bsrc  = Bw + (size_t)(t >> 5) * CMID + n0 + (t & 31) * 4;
    float* bdst0 = &Bs[0][0][0] + t * 4;   // byte off = 16*t (lane-linear)
    float* bdst1 = &Bs[1][0][0] + t * 4;

    float4 c0a{0,0,0,0}, c0b{0,0,0,0}, c1a{0,0,0,0}, c1b{0,0,0,0};
    float4 c2a{0,0,0,0}, c2b{0,0,0,0}, c3a{0,0,0,0}, c3b{0,0,0,0};
    float4 c4a{0,0,0,0}, c4b{0,0,0,0}, c5a{0,0,0,0}, c5b{0,0,0,0};
    float4 c6a{0,0,0,0}, c6b{0,0,0,0}, c7a{0,0,0,0}, c7b{0,0,0,0};

    // ---- prologue: tile 0 into buf 0 ----
    gld_lds16(bsrc, bdst0);
    gld_lds16(bsrc + 8 * CMID, bdst0 + 1024);
    float4 pa0 = *(const float4*)(asrc0);
    float4 pa1 = *(const float4*)(asrc1);
    As[0][ac0 + 0][ar0] = pa0.x; As[0][ac0 + 1][ar0] = pa0.y;
    As[0][ac0 + 2][ar0] = pa0.z; As[0][ac0 + 3][ar0] = pa0.w;
    As[0][ac0 + 0][ar0 + 64] = pa1.x; As[0][ac0 + 1][ar0 + 64] = pa1.y;
    As[0][ac0 + 2][ar0 + 64] = pa1.z; As[0][ac0 + 3][ar0 + 64] = pa1.w;
    __syncthreads();

#define FMA4(acc, s, b) { acc.x += (s)*(b).x; acc.y += (s)*(b).y; \
                          acc.z += (s)*(b).z; acc.w += (s)*(b).w; }

    for (int kt = 0; kt < 64; ++kt) {
        const int cur = kt & 1, nxt = cur ^ 1;
        if (kt < 63) {
            const int k0 = (kt + 1) * 16;
            float* bd = nxt ? bdst1 : bdst0;
            gld_lds16(bsrc + (size_t)k0 * CMID, bd);
            gld_lds16(bsrc + (size_t)(k0 + 8) * CMID, bd + 1024);
            pa0 = *(const float4*)(asrc0 + k0);
            pa1 = *(const float4*)(asrc1 + k0);
        }
#pragma unroll 2
        for (int kk = 0; kk < 16; ++kk) {
            float4 a0 = *(const float4*)&As[cur][kk][ty * 4];
            float4 a1 = *(const float4*)&As[cur][kk][64 + ty * 4];
            float4 b0 = *(const float4*)&Bs[cur][kk][tx * 4];
            float4 b1 = *(const float4*)&Bs[cur][kk][64 + tx * 4];
            FMA4(c0a, a0.x, b0) FMA4(c0b, a0.x, b1)
            FMA4(c1a, a0.y, b0) FMA4(c1b, a0.y, b1)
            FMA4(c2a, a0.z, b0) FMA4(c2b, a0.z, b1)
            FMA4(c3a, a0.w, b0) FMA4(c3b, a0.w, b1)
            FMA4(c4a, a1.x, b0) FMA4(c4b, a1.x, b1)
            FMA4(c5a, a1.y, b0) FMA4(c5b, a1.y, b1)
            FMA4(c6a, a1.z, b0) FMA4(c6b, a1.z, b1)
            FMA4(c7a, a1.w, b0) FMA4(c7b, a1.w, b1)
        }
        if (kt < 63) {
            As[nxt][ac0 + 0][ar0] = pa0.x; As[nxt][ac0 + 1][ar0] = pa0.y;
            As[nxt][ac0 + 2][ar0] = pa0.z; As[nxt][ac0 + 3][ar0] = pa0.w;
            As[nxt][ac0 + 0][ar0 + 64] = pa1.x; As[nxt][ac0 + 1][ar0 + 64] = pa1.y;
            As[nxt][ac0 + 2][ar0 + 64] = pa1.z; As[nxt][ac0 + 3][ar0 + 64] = pa1.w;
        }
        __syncthreads();
    }
#undef FMA4

    const float4 bias0 = *(const float4*)(bias + n0 + tx * 4);
    const float4 bias1 = *(const float4*)(bias + n0 + 64 + tx * 4);
#define STROW(row, ca, cb) { \
    float4 o; \
    o.x = fmaxf(ca.x + bias0.x, 0.f); o.y = fmaxf(ca.y + bias0.y, 0.f); \
    o.z = fmaxf(ca.z + bias0.z, 0.f); o.w = fmaxf(ca.w + bias0.w, 0.f); \
    *(float4*)(C + (size_t)(row) * CMID + n0 + tx * 4) = o; \
    o.x = fmaxf(cb.x + bias1.x, 0.f); o.y = fmaxf(cb.y + bias1.y, 0.f); \
    o.z = fmaxf(cb.z + bias1.z, 0.f); o.w = fmaxf(cb.w + bias1.w, 0.f); \
    *(float4*)(C + (size_t)(row) * CMID + n0 + 64 + tx * 4) = o; }

    const int mr = m0 + ty * 4;
    STROW(mr + 0, c0a, c0b)   STROW(mr + 1, c1a, c1b)
    STROW(mr + 2, c2a, c2b)   STROW(mr + 3, c3a, c3b)
    STROW(mr + 64, c4a, c4b)  STROW(mr + 65, c5a, c5b)
    STROW(mr + 66, c6a, c6b)  STROW(mr + 67, c7a, c7b)
#undef STROW
}

// =====================================================================
// wprep: combined weight matrix wcomb[512][48]: cols 0..8 = w_cls,
// 9..44 = w_reg, 45..47 = 0.
// =====================================================================
__global__ __launch_bounds__(256) void wprep_kernel(
    const float* __restrict__ wcls, const float* __restrict__ wreg,
    float* __restrict__ wcomb)
{
    int i = blockIdx.x * 256 + threadIdx.x;    // < 24576
    int k = i / 48, o = i - k * 48;
    float v = 0.f;
    if (o < 9)       v = wcls[k * 9 + o];
    else if (o < 45) v = wreg[k * 36 + (o - 9)];
    wcomb[i] = v;
}

// =====================================================================
// GEMM2: logits[16384 x 48(45)] = h @ wcomb. 64 px/block, 256 blocks,
// 12 outs/thread.
// =====================================================================
__global__ __launch_bounds__(256) void gemm2_kernel(
    const float* __restrict__ h, const float* __restrict__ wcomb,
    const float* __restrict__ bcls, const float* __restrict__ breg,
    float* __restrict__ logits)
{
    __shared__ float hS[64][33];   // padded
    __shared__ float wS[32][48];

    const int t  = threadIdx.x;
    const int p0 = blockIdx.x * 64;
    const int px = t & 63;
    const int og = t >> 6;          // 0..3 -> outs og*12 .. og*12+11

    const int hr = t >> 2;          // stage row 0..63
    const int hc = (t & 3) * 4;     // stage col

    float acc[12] = {};

    for (int kt = 0; kt < 16; ++kt) {
        const int k0 = kt * 32;
        {   // stage h tile 64x32 (2 float4/thread)
            const float* hp = h + (size_t)(p0 + hr) * CMID + k0 + hc;
            float4 v0 = *(const float4*)(hp);
            float4 v1 = *(const float4*)(hp + 16);
            hS[hr][hc + 0] = v0.x; hS[hr][hc + 1] = v0.y;
            hS[hr][hc + 2] = v0.z; hS[hr][hc + 3] = v0.w;
            hS[hr][16 + hc + 0] = v1.x; hS[hr][16 + hc + 1] = v1.y;
            hS[hr][16 + hc + 2] = v1.z; hS[hr][16 + hc + 3] = v1.w;
        }
        {   // stage w tile 32x48 = 384 float4
            int idx = t;
            if (idx < 384) {
                int kk = idx / 12, o4 = (idx - kk * 12) * 4;
                *(float4*)&wS[kk][o4] = *(const float4*)&wcomb[(size_t)(k0 + kk) * 48 + o4];
            }
            idx = t + 256;
            if (idx < 384) {
                int kk = idx / 12, o4 = (idx - kk * 12) * 4;
                *(float4*)&wS[kk][o4] = *(const float4*)&wcomb[(size_t)(k0 + kk) * 48 + o4];
            }
        }
        __syncthreads();
#pragma unroll 4
        for (int kk = 0; kk < 32; ++kk) {
            float hv = hS[px][kk];
            float4 w0 = *(const float4*)&wS[kk][og * 12];
            float4 w1 = *(const float4*)&wS[kk][og * 12 + 4];
            float4 w2 = *(const float4*)&wS[kk][og * 12 + 8];
            acc[0] += hv * w0.x; acc[1]  += hv * w0.y; acc[2]  += hv * w0.z; acc[3]  += hv * w0.w;
            acc[4] += hv * w1.x; acc[5]  += hv * w1.y; acc[6]  += hv * w1.z; acc[7]  += hv * w1.w;
            acc[8] += hv * w2.x; acc[9]  += hv * w2.y; acc[10] += hv * w2.z; acc[11] += hv * w2.w;
        }
        __syncthreads();
    }
#pragma unroll
    for (int c = 0; c < 12; ++c) {
        int o = og * 12 + c;
        if (o < 45) {
            float bv = (o < 9) ? bcls[o] : breg[o - 9];
            logits[(size_t)(p0 + px) * 48 + o] = acc[c] + bv;
        }
    }
}

// =====================================================================
// Decode: sigmoid -> cls_pred out; raw reg -> reg_pred out; box decode
// (clip [0,1]) -> boxes ws; 64-copy histogram of score upper-16 bits.
// =====================================================================
__global__ __launch_bounds__(256) void decode_kernel(
    const float* __restrict__ logits, const float4* __restrict__ ancs,
    float* __restrict__ out, float4* __restrict__ boxes,
    unsigned int* __restrict__ histN)
{
    int i = blockIdx.x * 256 + threadIdx.x;     // < 147456
    int p = i / 9, a = i - p * 9;
    const float* lrow = logits + (size_t)p * 48;
    float lg = lrow[a];
    float score = 1.f / (1.f + expf(-lg));
    out[CLS_OFF + i] = score;

    float r0 = lrow[9 + a * 4 + 0];
    float r1 = lrow[9 + a * 4 + 1];
    float r2 = lrow[9 + a * 4 + 2];
    float r3 = lrow[9 + a * 4 + 3];
    float4 rg; rg.x = r0; rg.y = r1; rg.z = r2; rg.w = r3;
    *(float4*)(out + REG_OFF + (size_t)i * 4) = rg;

    float4 an = ancs[i];
    float cx = an.x + r0 * an.z;
    float cy = an.y + r1 * an.w;
    float ww = an.z * expf(r2);
    float hh = an.w * expf(r3);
    float4 bb;
    bb.x = fminf(fmaxf(cx - ww * 0.5f, 0.f), 1.f);
    bb.y = fminf(fmaxf(cy - hh * 0.5f, 0.f), 1.f);
    bb.z = fminf(fmaxf(cx + ww * 0.5f, 0.f), 1.f);
    bb.w = fminf(fmaxf(cy + hh * 0.5f, 0.f), 1.f);
    boxes[i] = bb;

    unsigned int sb = __float_as_uint(score);   // positive -> bit-monotone
    atomicAdd(&histN[(unsigned)(blockIdx.x & (NHCOPY - 1)) * 65536u + (sb >> 16)], 1u);
}

// =====================================================================
// Histogram reduce: hist[b] = sum over 64 copies.
// =====================================================================
__global__ __launch_bounds__(256) void hreduce_kernel(
    const unsigned int* __restrict__ histN, unsigned int* __restrict__ hist)
{
    int b = blockIdx.x * 256 + threadIdx.x;    // < 65536
    unsigned int s = 0;
#pragma unroll 8
    for (int c = 0; c < NHCOPY; ++c) s += histN[(unsigned)c * 65536u + b];
    hist[b] = s;
}

// =====================================================================
// Scan: find threshold bin T = max bin with cum(>=T) >= PRE_NMS.
// =====================================================================
__global__ __launch_bounds__(256) void scan_kernel(
    const unsigned int* __restrict__ hist, unsigned int* __restrict__ meta)
{
    __shared__ unsigned int sums[256];
    __shared__ unsigned int sc[256];
    __shared__ unsigned int sc2[256];
    __shared__ int cstar;
    __shared__ unsigned int saShared;
    __shared__ int tbin;

    int t = threadIdx.x;
    if (t == 0) tbin = -1;

    unsigned int s = 0;
    int base = t << 8;
    for (int b = 0; b < 256; b += 4) {
        uint4 v = *(const uint4*)(hist + base + b);
        s += v.x + v.y + v.z + v.w;
    }
    sums[t] = s;
    __syncthreads();

    sc[t] = sums[255 - t];
    __syncthreads();
    for (int off = 1; off < 256; off <<= 1) {
        unsigned int v = sc[t];
        unsigned int add = (t >= off) ? sc[t - off] : 0u;
        __syncthreads();
        sc[t] = v + add;
        __syncthreads();
    }
    {
        unsigned int sa = (t == 255) ? 0u : sc[254 - t];
        if (sa < PRE_NMS && sa + sums[t] >= PRE_NMS) { cstar = t; saShared = sa; }
    }
    __syncthreads();

    int c = cstar;
    unsigned int SA = saShared;
    sc2[t] = hist[c * 256 + 255 - t];
    __syncthreads();
    for (int off = 1; off < 256; off <<= 1) {
        unsigned int v = sc2[t];
        unsigned int add = (t >= off) ? sc2[t - off] : 0u;
        __syncthreads();
        sc2[t] = v + add;
        __syncthreads();
    }
    {
        unsigned int si = sc2[255 - t];
        int cand = (SA + si >= PRE_NMS) ? t : -1;
        atomicMax(&tbin, cand);
    }
    __syncthreads();
    if (t == 0) meta[1] = (unsigned int)(c * 256 + tbin);
}

// =====================================================================
// Collect: all anchors with score bin >= T -> composite sort keys.
// key = score_bits<<32 | (0xFFFFFFFF - idx): larger == (higher score,
// then lower idx) -> matches stable argsort(-score).
// =====================================================================
__global__ __launch_bounds__(256) void collect_kernel(
    const float* __restrict__ scores, const unsigned int* __restrict__ meta,
    unsigned long long* __restrict__ coll, unsigned int* __restrict__ cnt)
{
    int i = blockIdx.x * 256 + threadIdx.x;
    unsigned int T = meta[1];
    unsigned int sb = __float_as_uint(scores[i]);
    if ((sb >> 16) >= T) {
        unsigned int pos = atomicAdd(cnt, 1u);
        if (pos < CAP_COLL)
            coll[pos] = ((unsigned long long)sb << 32) |
                        (unsigned long long)(0xFFFFFFFFu - (unsigned int)i);
    }
}

// =====================================================================
// Rank v3: rank(k) = #{keys > k} (keys unique) -> exact permutation;
// scatter box straight to sorted slot.
// R7 LDS version: 3 instr PER comparison (ds_read+cmp+add) ~80us.
// R8 scalar version: serially-dependent s_load chain, ~250cyc each ~290us.
// v3: __ballot = 64 comparisons per v_cmp. Lane holds key coll[j+lane]
// (one coalesced 8B load per 64 keys, L2-resident); wave owns 16 me's;
// per chunk per me: rank += popcll(ballot(k > me)) = ~3 instr / 64 cmp.
// 512 waves (128 blocks); ~6.5K instr/wave -> ~10us wall.
// =====================================================================
__global__ __launch_bounds__(256) void rank_kernel(
    const unsigned long long* __restrict__ coll,
    const unsigned int* __restrict__ cnt,
    const float4* __restrict__ boxes, float4* __restrict__ sboxes)
{
    const int t = threadIdx.x;
    const int lane = t & 63;
    const int gwave = blockIdx.x * 4 + (t >> 6);   // 0..511, 16 me's each
    unsigned int n = cnt[0];
    if (n > CAP_COLL) n = CAP_COLL;
    if (gwave * 16 >= (int)n) return;              // wave-uniform exit

    unsigned long long me[16];
    int rank[16];
#pragma unroll
    for (int i = 0; i < 16; ++i) {
        int mi = gwave * 16 + i;
        me[i] = (mi < (int)n) ? coll[mi] : ~0ULL;  // sentinel: nothing > ~0
        rank[i] = 0;
    }

    for (int j = 0; j < CAP_COLL; j += 64) {
        // guard: entries >= n are 0xAA poison (re-poisoned each call)
        unsigned long long k = ((unsigned)(j + lane) < n) ? coll[j + lane] : 0ULL;
#pragma unroll
        for (int i = 0; i < 16; ++i)
            rank[i] += (int)__popcll(__ballot(k > me[i]));
    }

#pragma unroll
    for (int i = 0; i < 16; ++i) {
        int mi = gwave * 16 + i;
        // rank[i] is wave-uniform; lane i does this me's gather+store so
        // the 16 box loads issue in parallel across lanes.
        if (mi < (int)n && rank[i] < PRE_NMS && lane == i) {
            unsigned int idx = 0xFFFFFFFFu - (unsigned int)(me[i] & 0xFFFFFFFFULL);
            if (idx > NANC - 1) idx = NANC - 1;   // safety clamp
            sboxes[rank[i]] = boxes[idx];
        }
    }
}

// =====================================================================
// NMS matrix build: strict-upper suppression bitmask.
// mask[r][cb] bit i set <=> j = cb*64+i, j > r, IoU(r,j) > 0.7.
// =====================================================================
__global__ __launch_bounds__(64) void nmsmat_kernel(
    const float4* __restrict__ sboxes, unsigned long long* __restrict__ mask)
{
    const int rb = blockIdx.x, cb = blockIdx.y;
    if (cb < rb) return;
    __shared__ float cx1[64], cy1[64], cx2[64], cy2[64], car[64];

    const int t = threadIdx.x;
    const int c = cb * 64 + t;
    float4 b = (c < PRE_NMS) ? sboxes[c] : make_float4(0.f, 0.f, 0.f, 0.f);
    cx1[t] = b.x; cy1[t] = b.y; cx2[t] = b.z; cy2[t] = b.w;
    car[t] = (b.z - b.x) * (b.w - b.y);
    __syncthreads();

    const int r = rb * 64 + t;
    if (r >= PRE_NMS) return;
    const float4 rbx = sboxes[r];
    const float ra = (rbx.z - rbx.x) * (rbx.w - rbx.y);

    unsigned long long w = 0ULL;
#pragma unroll 8
    for (int i = 0; i < 64; ++i) {
        int j = cb * 64 + i;
        float iw = fmaxf(fminf(rbx.z, cx2[i]) - fmaxf(rbx.x, cx1[i]), 0.f);
        float ih = fmaxf(fminf(rbx.w, cy2[i]) - fmaxf(rbx.y, cy1[i]), 0.f);
        float inter = iw * ih;
        float uni = ra + car[i] - inter;
        float iou = (uni > 0.f) ? (inter / uni) : 0.f;   // dummy j>=6000 -> 0
        if (iou > IOU_THR && j > r) w |= (1ULL << i);
    }
    mask[(size_t)r * NWORDS + cb] = w;
}

// =====================================================================
// NMS resolve: ONE wave, valid bitmask in registers (lane t owns words
// 2t, 2t+1). Row fetched as ONE dwordx4 per lane; words < wg (incl.
// never-written lower-triangle poison) are discarded by the predicate
// AFTER the load. __ballot arg must be a bool-ized compare (R4 bug).
// =====================================================================
__global__ __launch_bounds__(64) void nmsresolve_kernel(
    const float4* __restrict__ sboxes,
    const unsigned long long* __restrict__ mask,
    float* __restrict__ prop)
{
    const int t = threadIdx.x;      // one wave
    for (int j = t; j < POST_NMS * 4; j += 64) prop[j] = 0.f;

    const int w0 = 2 * t, w1 = 2 * t + 1;
    unsigned long long v0 = 0ULL, v1 = 0ULL;
    if (w0 < 93) v0 = ~0ULL; else if (w0 == 93) v0 = (1ULL << 48) - 1ULL;
    if (w1 < 93) v1 = ~0ULL; else if (w1 == 93) v1 = (1ULL << 48) - 1ULL;

    int cnt = 0;
    while (cnt < POST_NMS) {
        int c = 0x7fffffff;
        if (v0) c = (w0 << 6) + __builtin_ctzll(v0);
        else if (v1) c = (w1 << 6) + __builtin_ctzll(v1);
        unsigned long long bal = __ballot((v0 | v1) != 0ULL);
        if (!bal) break;
        int F = __builtin_ctzll(bal);
        int g = __shfl(c, F, 64);
        const int wg = g >> 6, bg = g & 63;

        if (t == 0) {
            float4 bb = sboxes[g];
            *(float4*)(prop + cnt * 4) = bb;
        }
        unsigned long long mx = 0ULL, my = 0ULL;
        if (t < 47) {   // 94 words = 47 ulonglong2
            const ulonglong2* row2 = (const ulonglong2*)(mask + (size_t)g * NWORDS);
            ulonglong2 mm = row2[t];
            mx = mm.x; my = mm.y;
        }
        unsigned long long m0 = (w0 >= wg) ? mx : 0ULL;
        unsigned long long m1 = (w1 >= wg) ? my : 0ULL;
        v0 &= ~m0; v1 &= ~m1;
        if (w0 == wg) v0 &= ~(1ULL << bg);
        if (w1 == wg) v1 &= ~(1ULL << bg);
        ++cnt;
    }
}

// =====================================================================
extern "C" void kernel_launch(void* const* d_in, const int* in_sizes, int n_in,
                              void* d_out, int out_size, void* d_ws, size_t ws_size,
                              hipStream_t stream)
{
    const float*  feats   = (const float*)d_in[0];
    const float4* ancs    = (const float4*)d_in[1];
    // d_in[2] = ancs_valid (unused by reference)
    const float*  w_bneck = (const float*)d_in[3];
    const float*  b_bneck = (const float*)d_in[4];
    const float*  w_cls   = (const float*)d_in[5];
    const float*  b_cls   = (const float*)d_in[6];
    const float*  w_reg   = (const float*)d_in[7];
    const float*  b_reg   = (const float*)d_in[8];

    float* out = (float*)d_out;
    char*  ws  = (char*)d_ws;
    float*              h      = (float*)(ws + WS_H);
    float*              logits = (float*)(ws + WS_LOGITS);
    float4*             boxes  = (float4*)(ws + WS_BOXES);
    unsigned int*       histN  = (unsigned int*)(ws + WS_HISTN); // aliases h
    unsigned int*       hist   = (unsigned int*)(ws + WS_HIST);
    float*              wcomb  = (float*)(ws + WS_WCOMB);        // aliases hist
    unsigned int*       meta   = (unsigned int*)(ws + WS_META);
    unsigned long long* coll   = (unsigned long long*)(ws + WS_COLL);
    float4*             sboxes = (float4*)(ws + WS_SBOX);
    unsigned long long* mask   = (unsigned long long*)(ws + WS_MASK); // aliases h

    hipMemsetAsync(ws + WS_META, 0, 256, stream);

    wprep_kernel<<<96, 256, 0, stream>>>(w_cls, w_reg, wcomb);
    gemm1_kernel<<<dim3(128, 4), 256, 0, stream>>>(feats, w_bneck, b_bneck, h);
    gemm2_kernel<<<256, 256, 0, stream>>>(h, wcomb, b_cls, b_reg, logits);
    // histN region (aliases h) becomes dead only after gemm2 completes
    hipMemsetAsync(ws + WS_HISTN, 0, (size_t)NHCOPY * 65536 * 4, stream);
    decode_kernel<<<576, 256, 0, stream>>>(logits, ancs, out, boxes, histN);
    hreduce_kernel<<<256, 256, 0, stream>>>(histN, hist);
    scan_kernel<<<1, 256, 0, stream>>>(hist, meta);
    collect_kernel<<<576, 256, 0, stream>>>(out, meta, coll, &meta[0]);
    rank_kernel<<<128, 256, 0, stream>>>(coll, meta, boxes, sboxes);
    nmsmat_kernel<<<dim3(94, 94), 64, 0, stream>>>(sboxes, mask);
    nmsresolve_kernel<<<1, 64, 0, stream>>>(sboxes, mask, out + PROP_OFF);
}